// Round 2
// baseline (290.227 us; speedup 1.0000x reference)
//
#include <hip/hip_runtime.h>
#include <math.h>

#define N_NODES 100000
#define N_EDGES 1600000
#define IN_DIM  256
#define HIDDEN  64

// fusedA2 geometry: 512 blocks x 1024 thr = exactly 2 blocks/CU (full machine).
// blocks [0,128):   degree count via global atomics (3125 int4 groups each)
// blocks [128,512): v = W.w2 then stream s[n] = x[n].v (4 rows/wave, 16-lane groups)
#define DEGB   128
#define D_QPB  3125          // 400000 int4 groups / 128 blocks
#define SBLK   384

// ---------------------------------------------------------------------------
// K_A: fused degree-count + s-stream.
// deg role: 1.6M global int atomicAdds into cnt[] (memory-side L2, random,
//           avg 16/node). Reads dst exactly once (6.4 MB vs 25.6 MB hist).
// s role:   unchanged validated structure (102.4 MB x stream at near-peak BW).
// ---------------------------------------------------------------------------
__global__ void __launch_bounds__(1024) fusedA2_kernel(const float* __restrict__ x,
                                                       const float* __restrict__ W,
                                                       const float* __restrict__ w2,
                                                       const int4* __restrict__ dst4,
                                                       int* __restrict__ cnt,
                                                       float* __restrict__ s) {
    __shared__ __align__(16) float vsh[IN_DIM];
    const int bid = blockIdx.x, tid = threadIdx.x;
    if (bid < DEGB) {
        const int q0 = bid * D_QPB;
        for (int k = tid; k < D_QPB; k += 1024) {
            int4 d4 = dst4[q0 + k];
            atomicAdd(&cnt[d4.x], 1);
            atomicAdd(&cnt[d4.y], 1);
            atomicAdd(&cnt[d4.z], 1);
            atomicAdd(&cnt[d4.w], 1);
        }
    } else {
        if (tid < IN_DIM) {
            const float4* wr  = (const float4*)(W + tid * HIDDEN);
            const float4* w2r = (const float4*)w2;
            float acc = 0.f;
            #pragma unroll
            for (int j = 0; j < HIDDEN / 4; ++j) {
                float4 a = wr[j], q = w2r[j];
                acc += a.x * q.x + a.y * q.y + a.z * q.z + a.w * q.w;
            }
            vsh[tid] = acc;
        }
        __syncthreads();
        const int wid  = tid >> 6;           // wave id 0..15
        const int lane = tid & 63;
        const int g    = lane >> 4;          // row-in-quad 0..3
        const int l16  = lane & 15;
        const float4* vr = (const float4*)vsh;
        float4 vv0 = vr[l16];
        float4 vv1 = vr[l16 + 16];
        float4 vv2 = vr[l16 + 32];
        float4 vv3 = vr[l16 + 48];
        #pragma unroll 2
        for (int n0 = ((bid - DEGB) * 16 + wid) * 4; n0 < N_NODES; n0 += SBLK * 16 * 4) {
            const float4* xr = (const float4*)(x + (size_t)(n0 + g) * IN_DIM);
            float4 a0 = xr[l16];
            float4 a1 = xr[l16 + 16];
            float4 a2 = xr[l16 + 32];
            float4 a3 = xr[l16 + 48];
            float d = a0.x * vv0.x + a0.y * vv0.y + a0.z * vv0.z + a0.w * vv0.w
                    + a1.x * vv1.x + a1.y * vv1.y + a1.z * vv1.z + a1.w * vv1.w
                    + a2.x * vv2.x + a2.y * vv2.y + a2.z * vv2.z + a2.w * vv2.w
                    + a3.x * vv3.x + a3.y * vv3.y + a3.z * vv3.z + a3.w * vv3.w;
            d += __shfl_down(d, 8, 16);
            d += __shfl_down(d, 4, 16);
            d += __shfl_down(d, 2, 16);
            d += __shfl_down(d, 1, 16);
            if (l16 == 0) s[n0 + g] = d;
        }
    }
}

// ---------------------------------------------------------------------------
// K_B: dinv = rsqrt(cnt+1) (self-loop), t = dinv*s. 1 thread = 4 nodes.
// ---------------------------------------------------------------------------
__global__ void dinv_t_kernel(const int4* __restrict__ cnt4,
                              const float* __restrict__ s,
                              float* __restrict__ dinv, float* __restrict__ t) {
    int w = blockIdx.x * blockDim.x + threadIdx.x;
    if (w >= N_NODES / 4) return;
    int4 c4 = cnt4[w];
    float4 sv = ((const float4*)s)[w];
    float4 di, tv;
    di.x = rsqrtf((float)(c4.x + 1)); di.y = rsqrtf((float)(c4.y + 1));
    di.z = rsqrtf((float)(c4.z + 1)); di.w = rsqrtf((float)(c4.w + 1));
    tv.x = di.x * sv.x; tv.y = di.y * sv.y; tv.z = di.z * sv.z; tv.w = di.w * sv.w;
    ((float4*)dinv)[w] = di;
    ((float4*)t)[w] = tv;
}

// ---------------------------------------------------------------------------
// K_C: scatter u[dst] += t[src] via global float atomics (memory-side L2).
// Reads each edge array exactly once (12.8 MB total vs 102.4 MB hist path);
// t gathers are L2-resident (400 KB).
// ---------------------------------------------------------------------------
__global__ void __launch_bounds__(1024) scat_atomic_kernel(const int4* __restrict__ src4,
                                                           const int4* __restrict__ dst4,
                                                           const float* __restrict__ t,
                                                           float* __restrict__ u) {
    int g = blockIdx.x * 1024 + threadIdx.x;
    if (g >= N_EDGES / 4) return;
    int4 d4 = dst4[g];
    int4 s4 = src4[g];
    atomicAdd(&u[d4.x], t[s4.x]);
    atomicAdd(&u[d4.y], t[s4.y]);
    atomicAdd(&u[d4.z], t[s4.z]);
    atomicAdd(&u[d4.w], t[s4.w]);
}

// ---------------------------------------------------------------------------
// K_D: out = sigmoid(dinv*(u + dinv*s) + c), 1 thread = 4 nodes.
// ---------------------------------------------------------------------------
__global__ void final2_kernel(const float* __restrict__ u,
                              const float* __restrict__ dinv,
                              const float* __restrict__ s,
                              const float* __restrict__ b,
                              const float* __restrict__ w2,
                              const float* __restrict__ b2,
                              float* __restrict__ out) {
    float c = b2[0];
    #pragma unroll 8
    for (int j = 0; j < HIDDEN; ++j) c += b[j] * w2[j];
    int g = blockIdx.x * blockDim.x + threadIdx.x;
    if (g >= N_NODES / 4) return;
    float4 uv = ((const float4*)u)[g];
    float4 di = ((const float4*)dinv)[g];
    float4 sv = ((const float4*)s)[g];
    float4 o;
    o.x = 1.f / (1.f + expf(-(di.x * (uv.x + di.x * sv.x) + c)));
    o.y = 1.f / (1.f + expf(-(di.y * (uv.y + di.y * sv.y) + c)));
    o.z = 1.f / (1.f + expf(-(di.z * (uv.z + di.z * sv.z) + c)));
    o.w = 1.f / (1.f + expf(-(di.w * (uv.w + di.w * sv.w) + c)));
    ((float4*)out)[g] = o;
}

// ------------------------- fallback (R1, validated) -------------------------
__global__ void wv_kernel(const float* __restrict__ W, const float* __restrict__ b,
                          const float* __restrict__ w2, const float* __restrict__ b2,
                          float* __restrict__ v, float* __restrict__ c) {
    int i = threadIdx.x;
    float acc = 0.f;
    for (int j = 0; j < HIDDEN; ++j) acc += W[i * HIDDEN + j] * w2[j];
    v[i] = acc;
    if (i == 0) {
        float cc = b2[0];
        for (int j = 0; j < HIDDEN; ++j) cc += b[j] * w2[j];
        *c = cc;
    }
}
__global__ void s_kernel(const float* __restrict__ x, const float* __restrict__ v,
                         float* __restrict__ s) {
    const int wave = threadIdx.x >> 6;
    const int lane = threadIdx.x & 63;
    const int n = blockIdx.x * 4 + wave;
    const float4* xr = (const float4*)(x + (size_t)n * IN_DIM);
    const float4* vr = (const float4*)v;
    float4 a  = xr[lane];
    float4 vv = vr[lane];
    float d = a.x * vv.x + a.y * vv.y + a.z * vv.z + a.w * vv.w;
    #pragma unroll
    for (int off = 32; off > 0; off >>= 1) d += __shfl_down(d, off, 64);
    if (lane == 0) s[n] = d;
}
__global__ void deg_kernel(const int* __restrict__ dst, int* __restrict__ cnt) {
    int e = blockIdx.x * blockDim.x + threadIdx.x;
    if (e < N_EDGES) atomicAdd(&cnt[dst[e]], 1);
}
__global__ void dinv_kernel(const int* __restrict__ cnt, const float* __restrict__ s,
                            float* __restrict__ dinv, float* __restrict__ t) {
    int n = blockIdx.x * blockDim.x + threadIdx.x;
    if (n < N_NODES) {
        float di = rsqrtf((float)(cnt[n] + 1));
        dinv[n] = di;
        t[n] = di * s[n];
    }
}
__global__ void scatter_kernel(const int* __restrict__ src, const int* __restrict__ dst,
                               const float* __restrict__ t, float* __restrict__ u) {
    int e = blockIdx.x * blockDim.x + threadIdx.x;
    if (e < N_EDGES) atomicAdd(&u[dst[e]], t[src[e]]);
}
__global__ void final_kernel(const float* __restrict__ dinv, const float* __restrict__ u,
                             const float* __restrict__ s, const float* __restrict__ c,
                             float* __restrict__ out) {
    int n = blockIdx.x * blockDim.x + threadIdx.x;
    if (n < N_NODES) {
        float di = dinv[n];
        float pre = di * (u[n] + di * s[n]) + c[0];
        out[n] = 1.f / (1.f + expf(-pre));
    }
}
// ----------------------------------------------------------------------------

extern "C" void kernel_launch(void* const* d_in, const int* in_sizes, int n_in,
                              void* d_out, int out_size, void* d_ws, size_t ws_size,
                              hipStream_t stream) {
    const float* x   = (const float*)d_in[0];   // [N, 256]
    const int*   ei  = (const int*)  d_in[1];   // [2, E]: src then dst
    const float* W   = (const float*)d_in[2];   // [256, 64]
    const float* b   = (const float*)d_in[3];   // [64]
    const float* w2  = (const float*)d_in[4];   // [64]
    const float* b2  = (const float*)d_in[5];   // [1]
    float* out = (float*)d_out;

    const int* src = ei;
    const int* dst = ei + N_EDGES;

    float* ws = (float*)d_ws;
    float* s    = ws + 0;        // 100352
    float* t    = ws + 100352;   // 100352
    float* dinv = ws + 200704;   // 100352
    int*   cnt  = (int*)(ws + 301056);  // 100352 (zeroed)
    float* u    = ws + 401408;   // 100352 (zeroed)
    const size_t need_bytes = (size_t)501760 * 4;  // ~2 MB

    if (ws_size >= need_bytes) {
        // zero cnt + u (adjacent): 200704 words
        hipMemsetAsync((char*)d_ws + (size_t)301056 * 4, 0, (size_t)200704 * 4, stream);
        fusedA2_kernel<<<DEGB + SBLK, 1024, 0, stream>>>(x, W, w2, (const int4*)dst, cnt, s);
        dinv_t_kernel<<<(N_NODES / 4 + 255) / 256, 256, 0, stream>>>((const int4*)cnt, s,
                                                                     dinv, t);
        scat_atomic_kernel<<<(N_EDGES / 4 + 1023) / 1024, 1024, 0, stream>>>(
            (const int4*)src, (const int4*)dst, t, u);
        final2_kernel<<<(N_NODES / 4 + 255) / 256, 256, 0, stream>>>(u, dinv, s,
                                                                     b, w2, b2, out);
    } else {
        // fallback: validated device-atomic path
        float* v   = ws + 0;
        float* c   = ws + 256;
        float* sf  = ws + 512;
        float* tf  = ws + 100608;
        float* df  = ws + 200704;
        float* uu  = ws + 300800;
        int*   cn  = (int*)(ws + 400800);
        hipMemsetAsync((char*)d_ws + (size_t)300800 * 4, 0, (size_t)200000 * 4, stream);
        wv_kernel<<<1, 256, 0, stream>>>(W, b, w2, b2, v, c);
        s_kernel<<<N_NODES / 4, 256, 0, stream>>>(x, v, sf);
        deg_kernel<<<(N_EDGES + 255) / 256, 256, 0, stream>>>(dst, cn);
        dinv_kernel<<<(N_NODES + 255) / 256, 256, 0, stream>>>(cn, sf, df, tf);
        scatter_kernel<<<(N_EDGES + 255) / 256, 256, 0, stream>>>(src, dst, tf, uu);
        final_kernel<<<(N_NODES + 255) / 256, 256, 0, stream>>>(df, uu, sf, c, out);
    }
}

// Round 3
// 204.337 us; speedup vs baseline: 1.4203x; 1.4203x over previous
//
#include <hip/hip_runtime.h>
#include <math.h>

#define N_NODES 100000
#define N_EDGES 1600000
#define IN_DIM  256
#define HIDDEN  64

// ---- partition geometry ----------------------------------------------------
#define PB     128        // partition blocks
#define P_Q    3125       // int4 groups per pblock (12500 edges)
#define P_E    12500      // edges per pblock
#define NR     8          // dst ranges
#define RNG    12544      // nodes per range (8*12544 = 100352 >= 100000)
#define RW     3136       // byte-packed words per range (RNG/4)
#define NG     16         // scatter groups (each covers 8 pblocks)
#define G_PB   (PB / NG)  // pblocks per scatter block = 8
#define SBLK   384        // s-stream blocks in fusedA

// ---------------------------------------------------------------------------
// K_A (fused): blocks [0,128) counting-sort partition of edges by dst range;
// blocks [128,512) compute v = W.w2 then stream s[n] = x[n].v (4 rows/wave).
// Partition: pass1 counts per range (LDS atomics, 8 words, bank-parallel),
// prefix, pass2 re-reads (L2-hot) and writes compacted (dstlocal:u16, src:i32).
// ---------------------------------------------------------------------------
__global__ void __launch_bounds__(1024) fusedA3_kernel(const float* __restrict__ x,
                                                       const float* __restrict__ W,
                                                       const float* __restrict__ w2,
                                                       const int4* __restrict__ src4,
                                                       const int4* __restrict__ dst4,
                                                       unsigned short* __restrict__ sdst,
                                                       int* __restrict__ ssrc,
                                                       int* __restrict__ goff,
                                                       int* __restrict__ gcnt,
                                                       float* __restrict__ s) {
    __shared__ int bcnt[NR];
    __shared__ int boff[NR];
    __shared__ __align__(16) float vsh[IN_DIM];
    const int bid = blockIdx.x, tid = threadIdx.x;
    if (bid < PB) {
        const int pb = bid;
        const int q0 = pb * P_Q;
        if (tid < NR) bcnt[tid] = 0;
        __syncthreads();
        for (int k = tid; k < P_Q; k += 1024) {
            int4 d = dst4[q0 + k];
            atomicAdd(&bcnt[d.x / RNG], 1);
            atomicAdd(&bcnt[d.y / RNG], 1);
            atomicAdd(&bcnt[d.z / RNG], 1);
            atomicAdd(&bcnt[d.w / RNG], 1);
        }
        __syncthreads();
        if (tid == 0) {
            int run = 0;
            #pragma unroll
            for (int r = 0; r < NR; ++r) {
                boff[r] = run;
                goff[pb * NR + r] = run;
                gcnt[pb * NR + r] = bcnt[r];
                run += bcnt[r];
            }
        }
        __syncthreads();
        const size_t rbase = (size_t)pb * P_E;
        for (int k = tid; k < P_Q; k += 1024) {
            int4 d = dst4[q0 + k];            // L2-hot re-read
            int4 sv = src4[q0 + k];
            int r, slot;
            r = d.x / RNG; slot = atomicAdd(&boff[r], 1);
            sdst[rbase + slot] = (unsigned short)(d.x - r * RNG); ssrc[rbase + slot] = sv.x;
            r = d.y / RNG; slot = atomicAdd(&boff[r], 1);
            sdst[rbase + slot] = (unsigned short)(d.y - r * RNG); ssrc[rbase + slot] = sv.y;
            r = d.z / RNG; slot = atomicAdd(&boff[r], 1);
            sdst[rbase + slot] = (unsigned short)(d.z - r * RNG); ssrc[rbase + slot] = sv.z;
            r = d.w / RNG; slot = atomicAdd(&boff[r], 1);
            sdst[rbase + slot] = (unsigned short)(d.w - r * RNG); ssrc[rbase + slot] = sv.w;
        }
    } else {
        if (tid < IN_DIM) {
            const float4* wr  = (const float4*)(W + tid * HIDDEN);
            const float4* w2r = (const float4*)w2;
            float acc = 0.f;
            #pragma unroll
            for (int j = 0; j < HIDDEN / 4; ++j) {
                float4 a = wr[j], q = w2r[j];
                acc += a.x * q.x + a.y * q.y + a.z * q.z + a.w * q.w;
            }
            vsh[tid] = acc;
        }
        __syncthreads();
        const int wid  = tid >> 6;           // wave id 0..15
        const int lane = tid & 63;
        const int g    = lane >> 4;          // row-in-quad 0..3
        const int l16  = lane & 15;
        const float4* vr = (const float4*)vsh;
        float4 vv0 = vr[l16];
        float4 vv1 = vr[l16 + 16];
        float4 vv2 = vr[l16 + 32];
        float4 vv3 = vr[l16 + 48];
        #pragma unroll 2
        for (int n0 = ((bid - PB) * 16 + wid) * 4; n0 < N_NODES; n0 += SBLK * 16 * 4) {
            const float4* xr = (const float4*)(x + (size_t)(n0 + g) * IN_DIM);
            float4 a0 = xr[l16];
            float4 a1 = xr[l16 + 16];
            float4 a2 = xr[l16 + 32];
            float4 a3 = xr[l16 + 48];
            float d = a0.x * vv0.x + a0.y * vv0.y + a0.z * vv0.z + a0.w * vv0.w
                    + a1.x * vv1.x + a1.y * vv1.y + a1.z * vv1.z + a1.w * vv1.w
                    + a2.x * vv2.x + a2.y * vv2.y + a2.z * vv2.z + a2.w * vv2.w
                    + a3.x * vv3.x + a3.y * vv3.y + a3.z * vv3.z + a3.w * vv3.w;
            d += __shfl_down(d, 8, 16);
            d += __shfl_down(d, 4, 16);
            d += __shfl_down(d, 2, 16);
            d += __shfl_down(d, 1, 16);
            if (l16 == 0) s[n0 + g] = d;
        }
    }
}

// ---------------------------------------------------------------------------
// K_B: degree hist from partitioned u16 dst-locals, byte-packed LDS (12.5 KB).
// 128 blocks = 8 ranges x 16 groups; each block consumes 8 pblock segments.
// ---------------------------------------------------------------------------
__global__ void __launch_bounds__(1024) degp_kernel(const unsigned short* __restrict__ sdst,
                                                    const int* __restrict__ goff,
                                                    const int* __restrict__ gcnt,
                                                    unsigned* __restrict__ partialD) {
    __shared__ unsigned dcnt[RW];
    const int r = blockIdx.x & (NR - 1);
    const int g = blockIdx.x >> 3;
    for (int i = threadIdx.x; i < RW; i += 1024) dcnt[i] = 0u;
    __syncthreads();
    for (int pb = g * G_PB; pb < g * G_PB + G_PB; ++pb) {
        const size_t base = (size_t)pb * P_E + goff[pb * NR + r];
        const int cnt = gcnt[pb * NR + r];
        for (int k = threadIdx.x; k < cnt; k += 1024) {
            int dl = sdst[base + k];
            atomicAdd(&dcnt[dl >> 2], 1u << ((dl & 3) * 8));
        }
    }
    __syncthreads();
    unsigned* outp = partialD + (size_t)blockIdx.x * RW;
    for (int i = threadIdx.x; i < RW; i += 1024) outp[i] = dcnt[i];
}

// ---------------------------------------------------------------------------
// K_C: merge 16 byte-packed deg partials; dinv = rsqrt(deg+1), t = dinv*s.
// One thread per packed word (4 nodes). 98 blocks x 256 = 25088 words exactly.
// ---------------------------------------------------------------------------
__global__ void dinvp_kernel(const unsigned* __restrict__ partialD,
                             const float* __restrict__ s,
                             float* __restrict__ dinv, float* __restrict__ t) {
    const int w = blockIdx.x * blockDim.x + threadIdx.x;   // 0..25087
    const int r = w / RW, wl = w - r * RW;
    unsigned a0 = 0, a1 = 0, a2 = 0, a3 = 0;
    #pragma unroll 8
    for (int g = 0; g < NG; ++g) {
        unsigned p = partialD[(size_t)(g * NR + r) * RW + wl];
        a0 += p & 255u; a1 += (p >> 8) & 255u; a2 += (p >> 16) & 255u; a3 += p >> 24;
    }
    const int n0 = r * RNG + wl * 4;
    float4 sv = *(const float4*)(s + n0);
    float4 di, tv;
    di.x = rsqrtf((float)(a0 + 1)); di.y = rsqrtf((float)(a1 + 1));
    di.z = rsqrtf((float)(a2 + 1)); di.w = rsqrtf((float)(a3 + 1));
    tv.x = di.x * sv.x; tv.y = di.y * sv.y; tv.z = di.z * sv.z; tv.w = di.w * sv.w;
    *(float4*)(dinv + n0) = di;
    *(float4*)(t + n0) = tv;
}

// ---------------------------------------------------------------------------
// K_D: u-scatter from partitioned segments, float LDS hist (50 KB).
// 128 blocks = 8 ranges x 16 groups. Reads each edge exactly once.
// ---------------------------------------------------------------------------
__global__ void __launch_bounds__(1024) uscatp_kernel(const unsigned short* __restrict__ sdst,
                                                      const int* __restrict__ ssrc,
                                                      const int* __restrict__ goff,
                                                      const int* __restrict__ gcnt,
                                                      const float* __restrict__ t,
                                                      float* __restrict__ partialU) {
    __shared__ float ua[RNG];
    const int r = blockIdx.x & (NR - 1);
    const int g = blockIdx.x >> 3;
    for (int i = threadIdx.x; i < RNG; i += 1024) ua[i] = 0.f;
    __syncthreads();
    for (int pb = g * G_PB; pb < g * G_PB + G_PB; ++pb) {
        const size_t base = (size_t)pb * P_E + goff[pb * NR + r];
        const int cnt = gcnt[pb * NR + r];
        for (int k = threadIdx.x; k < cnt; k += 1024) {
            int dl = sdst[base + k];
            int sr = ssrc[base + k];
            atomicAdd(&ua[dl], t[sr]);      // t is L2-resident (400 KB)
        }
    }
    __syncthreads();
    float* outp = partialU + (size_t)blockIdx.x * RNG;
    for (int i = threadIdx.x; i < RNG; i += 1024) outp[i] = ua[i];
}

// ---------------------------------------------------------------------------
// K_E: merge 16 u partials + sigmoid. One thread per 4 nodes, 25088 groups.
// ---------------------------------------------------------------------------
__global__ void finalp_kernel(const float* __restrict__ partialU,
                              const float* __restrict__ dinv,
                              const float* __restrict__ s,
                              const float* __restrict__ b,
                              const float* __restrict__ w2,
                              const float* __restrict__ b2,
                              float* __restrict__ out) {
    float c = b2[0];
    #pragma unroll 8
    for (int j = 0; j < HIDDEN; ++j) c += b[j] * w2[j];
    const int w = blockIdx.x * blockDim.x + threadIdx.x;   // 0..25087
    const int r = w / RW, wl = w - r * RW;
    float4 u = make_float4(0.f, 0.f, 0.f, 0.f);
    #pragma unroll 8
    for (int g = 0; g < NG; ++g) {
        float4 p = *(const float4*)(partialU + (size_t)(g * NR + r) * RNG + wl * 4);
        u.x += p.x; u.y += p.y; u.z += p.z; u.w += p.w;
    }
    const int n0 = r * RNG + wl * 4;
    float4 di = *(const float4*)(dinv + n0);
    float4 sv = *(const float4*)(s + n0);
    float4 o;
    o.x = 1.f / (1.f + expf(-(di.x * (u.x + di.x * sv.x) + c)));
    o.y = 1.f / (1.f + expf(-(di.y * (u.y + di.y * sv.y) + c)));
    o.z = 1.f / (1.f + expf(-(di.z * (u.z + di.z * sv.z) + c)));
    o.w = 1.f / (1.f + expf(-(di.w * (u.w + di.w * sv.w) + c)));
    if (n0 + 3 < N_NODES) {
        *(float4*)(out + n0) = o;
    } else {
        if (n0 + 0 < N_NODES) out[n0 + 0] = o.x;
        if (n0 + 1 < N_NODES) out[n0 + 1] = o.y;
        if (n0 + 2 < N_NODES) out[n0 + 2] = o.z;
        if (n0 + 3 < N_NODES) out[n0 + 3] = o.w;
    }
}

// ------------------------- fallback (R1, validated) -------------------------
__global__ void wv_kernel(const float* __restrict__ W, const float* __restrict__ b,
                          const float* __restrict__ w2, const float* __restrict__ b2,
                          float* __restrict__ v, float* __restrict__ c) {
    int i = threadIdx.x;
    float acc = 0.f;
    for (int j = 0; j < HIDDEN; ++j) acc += W[i * HIDDEN + j] * w2[j];
    v[i] = acc;
    if (i == 0) {
        float cc = b2[0];
        for (int j = 0; j < HIDDEN; ++j) cc += b[j] * w2[j];
        *c = cc;
    }
}
__global__ void s_kernel(const float* __restrict__ x, const float* __restrict__ v,
                         float* __restrict__ s) {
    const int wave = threadIdx.x >> 6;
    const int lane = threadIdx.x & 63;
    const int n = blockIdx.x * 4 + wave;
    const float4* xr = (const float4*)(x + (size_t)n * IN_DIM);
    const float4* vr = (const float4*)v;
    float4 a  = xr[lane];
    float4 vv = vr[lane];
    float d = a.x * vv.x + a.y * vv.y + a.z * vv.z + a.w * vv.w;
    #pragma unroll
    for (int off = 32; off > 0; off >>= 1) d += __shfl_down(d, off, 64);
    if (lane == 0) s[n] = d;
}
__global__ void deg_kernel(const int* __restrict__ dst, int* __restrict__ cnt) {
    int e = blockIdx.x * blockDim.x + threadIdx.x;
    if (e < N_EDGES) atomicAdd(&cnt[dst[e]], 1);
}
__global__ void dinv_kernel(const int* __restrict__ cnt, const float* __restrict__ s,
                            float* __restrict__ dinv, float* __restrict__ t) {
    int n = blockIdx.x * blockDim.x + threadIdx.x;
    if (n < N_NODES) {
        float di = rsqrtf((float)(cnt[n] + 1));
        dinv[n] = di;
        t[n] = di * s[n];
    }
}
__global__ void scatter_kernel(const int* __restrict__ src, const int* __restrict__ dst,
                               const float* __restrict__ t, float* __restrict__ u) {
    int e = blockIdx.x * blockDim.x + threadIdx.x;
    if (e < N_EDGES) atomicAdd(&u[dst[e]], t[src[e]]);
}
__global__ void final_kernel(const float* __restrict__ dinv, const float* __restrict__ u,
                             const float* __restrict__ s, const float* __restrict__ c,
                             float* __restrict__ out) {
    int n = blockIdx.x * blockDim.x + threadIdx.x;
    if (n < N_NODES) {
        float di = dinv[n];
        float pre = di * (u[n] + di * s[n]) + c[0];
        out[n] = 1.f / (1.f + expf(-pre));
    }
}
// ----------------------------------------------------------------------------

extern "C" void kernel_launch(void* const* d_in, const int* in_sizes, int n_in,
                              void* d_out, int out_size, void* d_ws, size_t ws_size,
                              hipStream_t stream) {
    const float* x   = (const float*)d_in[0];   // [N, 256]
    const int*   ei  = (const int*)  d_in[1];   // [2, E]: src then dst
    const float* W   = (const float*)d_in[2];   // [256, 64]
    const float* b   = (const float*)d_in[3];   // [64]
    const float* w2  = (const float*)d_in[4];   // [64]
    const float* b2  = (const float*)d_in[5];   // [1]
    float* out = (float*)d_out;

    const int* src = ei;
    const int* dst = ei + N_EDGES;

    float* ws = (float*)d_ws;
    // word offsets
    float*          s        = ws + 0;          // 100352
    float*          t        = ws + 100352;     // 100352
    float*          dinv     = ws + 200704;     // 100352
    unsigned short* sdst     = (unsigned short*)(ws + 301056);   // 1.6M u16 = 800000 words
    int*            ssrc     = (int*)(ws + 1101056);             // 1.6M words
    int*            goff     = (int*)(ws + 2701056);             // 1024
    int*            gcnt     = (int*)(ws + 2702080);             // 1024
    unsigned*       partialD = (unsigned*)(ws + 2703104);        // 128*3136  = 401408
    float*          partialU = ws + 3104512;                     // 128*12544 = 1605632
    const size_t need_bytes = (size_t)4710144 * 4;               // ~18.8 MB

    if (ws_size >= need_bytes) {
        fusedA3_kernel<<<PB + SBLK, 1024, 0, stream>>>(x, W, w2, (const int4*)src,
                                                       (const int4*)dst, sdst, ssrc,
                                                       goff, gcnt, s);
        degp_kernel<<<NR * NG, 1024, 0, stream>>>(sdst, goff, gcnt, partialD);
        dinvp_kernel<<<98, 256, 0, stream>>>(partialD, s, dinv, t);
        uscatp_kernel<<<NR * NG, 1024, 0, stream>>>(sdst, ssrc, goff, gcnt, t, partialU);
        finalp_kernel<<<98, 256, 0, stream>>>(partialU, dinv, s, b, w2, b2, out);
    } else {
        // fallback: validated device-atomic path
        float* v   = ws + 0;
        float* c   = ws + 256;
        float* sf  = ws + 512;
        float* tf  = ws + 100608;
        float* df  = ws + 200704;
        float* uu  = ws + 300800;
        int*   cn  = (int*)(ws + 400800);
        hipMemsetAsync((char*)d_ws + (size_t)300800 * 4, 0, (size_t)200000 * 4, stream);
        wv_kernel<<<1, 256, 0, stream>>>(W, b, w2, b2, v, c);
        s_kernel<<<N_NODES / 4, 256, 0, stream>>>(x, v, sf);
        deg_kernel<<<(N_EDGES + 255) / 256, 256, 0, stream>>>(dst, cn);
        dinv_kernel<<<(N_NODES + 255) / 256, 256, 0, stream>>>(cn, sf, df, tf);
        scatter_kernel<<<(N_EDGES + 255) / 256, 256, 0, stream>>>(src, dst, tf, uu);
        final_kernel<<<(N_NODES + 255) / 256, 256, 0, stream>>>(df, uu, sf, c, out);
    }
}